// Round 1
// baseline (60061.719 us; speedup 1.0000x reference)
//
#include <hip/hip_runtime.h>
#include <hip/hip_bf16.h>

// LSTMModel_with_theta: B=64, T=2048, H=256, 2-layer LSTM -> mean_t -> MLP(512->256->256->1)
//
// Design (round 1): latency-bound sequential recurrence.
//  - Per layer: 128 WGs = 4 batch-groups (16 rows) x 32 unit-groups (8 units x 4 gates = 32 cols).
//  - Weights bf16 in LDS (XOR-swizzled), gate matmul via mfma_f32_16x16x32_bf16, fp32 accum.
//  - Cross-WG h exchange per step through global bf16 + per-(t,bg) counter flags
//    (threadfence release + atomicAdd / acquire spin). Flags memset to 0 each launch.
//  - h0 sequence stored fully in ws (bf16, 64MB) so layer 1 folds xg1 = h0@Wx1 into its K=512 MFMA.
//  - c/h state and h1-mean accumulator live in registers.

#define BB 64
#define TT 2048
#define HH 256
#define GG 1024
#define NBG 4
#define NUG 32
#define BT 16
#define UT 8

typedef short s16x8 __attribute__((ext_vector_type(8)));
typedef float f32x4 __attribute__((ext_vector_type(4)));

__device__ inline unsigned short f2bf(float f) {
  unsigned u = __float_as_uint(f);
  u += 0x7fff + ((u >> 16) & 1);          // round-to-nearest-even
  return (unsigned short)(u >> 16);
}
__device__ inline float sigm(float x) { return 1.f / (1.f + __expf(-x)); }
__device__ inline float tanh_f(float x) { return 1.f - 2.f / (__expf(2.f * x) + 1.f); }

__device__ inline void wait_ge(int* p, int tgt) {
  while (__hip_atomic_load(p, __ATOMIC_ACQUIRE, __HIP_MEMORY_SCOPE_AGENT) < tgt)
    __builtin_amdgcn_s_sleep(2);
}

// LAYER 0: KT=256 (Wa=Wh0). LAYER 1: KT=512 (rows 0..255 = Wx1, 256..511 = Wh1).
template<int LAYER, int KT>
__global__ __launch_bounds__(256)
void rec_kernel(const float* __restrict__ Wa, const float* __restrict__ Wb,
                const float* __restrict__ bias, const float* __restrict__ Wx0,
                const float* __restrict__ x,
                unsigned short* __restrict__ seq0, unsigned short* __restrict__ ring,
                float* __restrict__ hmean, int* flags0, int* flags1)
{
  __shared__ unsigned short Wlds[KT * 32];   // [col(32)][k(KT)] bf16, XOR-swizzled
  __shared__ float gbuf[2][2][BT][16];       // [ntile][khalf][brow][col16]
  __shared__ float xcur[BT];
  __shared__ float xvec[32];
  __shared__ float bvec[32];

  const int tid = threadIdx.x;
  const int wg  = blockIdx.x;
  const int bg  = wg & 3;         // batch group (16 rows)
  const int ug  = wg >> 2;        // unit group (8 hidden units)
  const int u0  = ug * UT;
  const int b0  = bg * BT;

  // ---- stage weight slice into LDS (bf16, swizzled) ----
  char* wbytes = (char*)Wlds;
  for (int id = tid; id < 32 * (KT / 8); id += 256) {
    int c  = id & 31;
    int k0 = (id >> 5) << 3;
    int gate = c >> 3, u = c & 7;
    int colfull = gate * 256 + u0 + u;
    union { s16x8 v; unsigned short s[8]; } tmp;
#pragma unroll
    for (int i = 0; i < 8; ++i) {
      int k = k0 + i;
      float wv;
      if (LAYER == 1 && k >= 256) wv = Wb[(size_t)(k - 256) * GG + colfull];
      else                        wv = Wa[(size_t)k * GG + colfull];
      tmp.s[i] = f2bf(wv);
    }
    int baddr = (c * (KT * 2) + k0 * 2) ^ ((c & 7) << 4);
    *(s16x8*)(wbytes + baddr) = tmp.v;
  }
  if (tid < 32) {
    int gate = tid >> 3, u = tid & 7;
    int colfull = gate * 256 + u0 + u;
    bvec[tid] = bias[colfull];
    if (LAYER == 0) xvec[tid] = Wx0[colfull];
  }
  __syncthreads();

  const int lane  = tid & 63;
  const int w     = tid >> 6;     // wave 0..3
  const int ntile = w & 1;        // cols 0-15 (gates i,f) / 16-31 (gates g,o)
  const int khalf = w >> 1;       // K split across waves
  const int arow  = lane & 15;    // A row (batch)
  const int kgrp  = lane >> 4;    // A/B k-group
  const int bcol  = lane & 15;    // B col within ntile
  const int c     = ntile * 16 + bcol;

  float creg = 0.f, hsum = 0.f;          // per-thread state (tid < 128)
  const int eb = tid >> 3, eu = tid & 7; // elementwise (batch,unit) mapping

  const int KS2 = KT / 64;               // k-steps per khalf (4 or 8)

  for (int t = 0; t < TT; ++t) {
    if (LAYER == 0 && tid < BT) xcur[tid] = x[(size_t)(b0 + tid) * TT + t];
    if (tid == 0) {
      if (LAYER == 0) { if (t > 0) wait_ge(&flags0[(t - 1) * NBG + bg], NUG); }
      else {
        wait_ge(&flags0[t * NBG + bg], NUG);
        if (t > 0) wait_ge(&flags1[(t - 1) * NBG + bg], NUG);
      }
    }
    __syncthreads();   // also makes acquire-invalidated L1 ordering apply to all waves

    f32x4 acc = {0.f, 0.f, 0.f, 0.f};
    if (!(LAYER == 0 && t == 0)) {
#pragma unroll
      for (int i = 0; i < KS2; ++i) {
        int ks = khalf * KS2 + i;
        int k  = ks * 32 + kgrp * 8;
        s16x8 av = {0, 0, 0, 0, 0, 0, 0, 0};
        if (LAYER == 1 && k >= 256) {
          if (t > 0)
            av = *(const s16x8*)(ring + ((size_t)((t + 1) & 1) * BB + b0 + arow) * HH + (k - 256));
        } else {
          int trow = (LAYER == 0) ? (t - 1) : t;
          av = *(const s16x8*)(seq0 + ((size_t)trow * BB + b0 + arow) * HH + k);
        }
        int baddr = (c * (KT * 2) + k * 2) ^ ((c & 7) << 4);
        s16x8 bv = *(const s16x8*)(wbytes + baddr);
        acc = __builtin_amdgcn_mfma_f32_16x16x32_bf16(av, bv, acc, 0, 0, 0);
      }
    }
#pragma unroll
    for (int r = 0; r < 4; ++r) {
      float v = acc[r];
      if (khalf == 0) {                      // bias/xg added once
        int brow = kgrp * 4 + r;
        v += bvec[c];
        if (LAYER == 0) v += xcur[brow] * xvec[c];
      }
      gbuf[ntile][khalf][kgrp * 4 + r][bcol] = v;
    }
    __syncthreads();

    if (tid < BT * UT) {
      float gi = gbuf[0][0][eb][eu]      + gbuf[0][1][eb][eu];
      float gf = gbuf[0][0][eb][8 + eu]  + gbuf[0][1][eb][8 + eu];
      float gg = gbuf[1][0][eb][eu]      + gbuf[1][1][eb][eu];
      float go = gbuf[1][0][eb][8 + eu]  + gbuf[1][1][eb][8 + eu];
      float iv = sigm(gi), fv = sigm(gf), gv = tanh_f(gg), ov = sigm(go);
      creg = fv * creg + iv * gv;
      float h = ov * tanh_f(creg);
      unsigned short hb = f2bf(h);
      if (LAYER == 0) seq0[((size_t)t * BB + b0 + eb) * HH + u0 + eu] = hb;
      else { ring[((size_t)(t & 1) * BB + b0 + eb) * HH + u0 + eu] = hb; hsum += h; }
    }
    __threadfence();        // release h block to agent scope
    __syncthreads();
    if (tid == 0) {
      int* f = (LAYER == 0) ? &flags0[t * NBG + bg] : &flags1[t * NBG + bg];
      __hip_atomic_fetch_add(f, 1, __ATOMIC_RELEASE, __HIP_MEMORY_SCOPE_AGENT);
    }
  }

  if (LAYER == 1 && tid < BT * UT)
    hmean[(size_t)(b0 + eb) * HH + u0 + eu] = hsum * (1.f / TT);
}

__global__ __launch_bounds__(256)
void mlp_kernel(const float* __restrict__ theta, const float* __restrict__ Wtp,
                const float* __restrict__ btp, const float* __restrict__ Wl1,
                const float* __restrict__ bl1, const float* __restrict__ Wl2,
                const float* __restrict__ bl2, const float* __restrict__ Wo,
                const float* __restrict__ bo, const float* __restrict__ hmean,
                float* __restrict__ out)
{
  const int b = blockIdx.x;
  const int j = threadIdx.x;        // 256 threads = output cols
  __shared__ float z[2 * HH];
  __shared__ float z1s[HH];
  __shared__ float red[256];

  float tp = btp[j];
#pragma unroll
  for (int d = 0; d < 5; ++d) tp += theta[b * 5 + d] * Wtp[d * HH + j];
  z[j] = hmean[(size_t)b * HH + j];
  z[HH + j] = tp;
  __syncthreads();

  float a1 = bl1[j];
  for (int k = 0; k < 2 * HH; ++k) a1 += z[k] * Wl1[(size_t)k * 256 + j];
  a1 = (a1 > 0.f) ? a1 : (__expf(a1) - 1.f);
  z1s[j] = a1;
  __syncthreads();

  float a2 = bl2[j];
  for (int k = 0; k < HH; ++k) a2 += z1s[k] * Wl2[(size_t)k * 256 + j];
  a2 = (a2 > 0.f) ? a2 : (__expf(a2) - 1.f);
  red[j] = a2 * Wo[j];
  __syncthreads();
  for (int s = 128; s > 0; s >>= 1) {
    if (j < s) red[j] += red[j + s];
    __syncthreads();
  }
  if (j == 0) out[b] = red[0] + bo[0];
}

extern "C" void kernel_launch(void* const* d_in, const int* in_sizes, int n_in,
                              void* d_out, int out_size, void* d_ws, size_t ws_size,
                              hipStream_t stream) {
  const float* x    = (const float*)d_in[0];
  const float* theta= (const float*)d_in[1];
  const float* Wx0  = (const float*)d_in[2];
  const float* Wh0  = (const float*)d_in[3];
  const float* b0   = (const float*)d_in[4];
  const float* Wx1  = (const float*)d_in[5];
  const float* Wh1  = (const float*)d_in[6];
  const float* b1   = (const float*)d_in[7];
  const float* Wtp  = (const float*)d_in[8];
  const float* btp  = (const float*)d_in[9];
  const float* Wl1  = (const float*)d_in[10];
  const float* bl1  = (const float*)d_in[11];
  const float* Wl2  = (const float*)d_in[12];
  const float* bl2  = (const float*)d_in[13];
  const float* Wo   = (const float*)d_in[14];
  const float* bo   = (const float*)d_in[15];

  // ws layout: flags0[T*4] | flags1[T*4] | h1 ring bf16 [2][64][256] | hmean f32 [64][256] | h0 seq bf16 [T][64][256]
  char* ws = (char*)d_ws;
  int* flags0 = (int*)ws;
  int* flags1 = (int*)(ws + 32768);
  unsigned short* ring  = (unsigned short*)(ws + 65536);
  float* hmean          = (float*)(ws + 131072);
  unsigned short* seq0  = (unsigned short*)(ws + 196608);
  const size_t WS_NEED = 196608ull + (size_t)TT * BB * HH * 2ull;
  if (ws_size < WS_NEED) return;   // fail visibly (d_out stays poisoned)

  hipMemsetAsync(d_ws, 0, 65536, stream);   // reset flags each launch (replay-deterministic)

  rec_kernel<0, 256><<<dim3(NBG * NUG), dim3(256), 0, stream>>>(
      Wh0, nullptr, b0, Wx0, x, seq0, ring, hmean, flags0, flags1);
  rec_kernel<1, 512><<<dim3(NBG * NUG), dim3(256), 0, stream>>>(
      Wx1, Wh1, b1, nullptr, nullptr, seq0, ring, hmean, flags0, flags1);
  mlp_kernel<<<dim3(BB), dim3(256), 0, stream>>>(
      theta, Wtp, btp, Wl1, bl1, Wl2, bl2, Wo, bo, hmean, (float*)d_out);
}

// Round 2
// 21144.914 us; speedup vs baseline: 2.8405x; 2.8405x over previous
//
#include <hip/hip_runtime.h>
#include <hip/hip_bf16.h>

// LSTMModel_with_theta: B=64, T=2048, H=256, 2-layer LSTM -> mean_t -> MLP.
//
// Round 2: batch-partitioned recurrence, weights resident in VGPRs.
//  - Layer 0: 8 WGs = 4 batch-groups x 2 column-halves (512 cols, K=256).
//  - Layer 1: 16 WGs = 4 batch-groups x 4 column-quarters (256 cols, K=512:
//    h0_t (Wx1) || h1_{t-1} (Wh1) fused in one MFMA K-loop).
//  - Per-WG weight slice (256KB bf16) lives in 128 VGPRs/lane (8 waves).
//  - Sync: single-writer monotonic flag counters; RELAXED.. well ACQUIRE polls
//    + one RELEASE atomicAdd per WG per step (one wbl2/step, not 8).
//  - Both layers co-scheduled in ONE kernel launch (48 blocks; blocks with
//    g>=4 exit). Layer 1 trails layer 0 through append-only seq0 (no back-pressure).

#define BB 64
#define TT 2048
#define HH 256

typedef short s16x8 __attribute__((ext_vector_type(8)));
typedef float f32x4 __attribute__((ext_vector_type(4)));

__device__ inline unsigned short f2bf(float f) {
  unsigned u = __float_as_uint(f);
  u += 0x7fff + ((u >> 16) & 1);          // RNE
  return (unsigned short)(u >> 16);
}
__device__ inline float sigm(float x) { return 1.f / (1.f + __expf(-x)); }
__device__ inline float tanh_f(float x) { return 1.f - 2.f / (__expf(2.f * x) + 1.f); }

__device__ inline void wait_ge(int* p, int tgt) {
  while (__hip_atomic_load(p, __ATOMIC_ACQUIRE, __HIP_MEMORY_SCOPE_AGENT) < tgt)
    __builtin_amdgcn_s_sleep(1);
}

#define MFMA(a, b, c) __builtin_amdgcn_mfma_f32_16x16x32_bf16((a), (b), (c), 0, 0, 0)

__global__ __launch_bounds__(512, 2)
void lstm_kernel(const float* __restrict__ Wx0, const float* __restrict__ Wh0,
                 const float* __restrict__ b0v,
                 const float* __restrict__ Wx1, const float* __restrict__ Wh1,
                 const float* __restrict__ b1v,
                 const float* __restrict__ x,
                 unsigned short* __restrict__ seq0, unsigned short* __restrict__ ring,
                 float* __restrict__ hmean, int* flags)
{
  const int bid  = blockIdx.x;
  const int g    = bid & 7;        // batch group (XCD-pairing heuristic: partners share bid%8)
  const int role = bid >> 3;       // 0,1: layer0 half; 2..5: layer1 quarter
  if (g >= 4 || role > 5) return;

  __shared__ __align__(16) char smem[16 * 264 * 4];   // L0: h dbuf (8KB) | L1: gbuf (16.9KB)

  const int tid  = threadIdx.x;
  const int lane = tid & 63;
  const int w    = tid >> 6;       // wave 0..7
  const int u16  = lane & 15;      // col-in-tile / A-row
  const int kgrp = lane >> 4;      // k-subgroup
  const int arow = lane & 15;      // A row (batch row in group)
  const int b0r  = g * 16;

  int* L0f = flags + g * 32;              // [half] stride 16 ints
  int* L1f = flags + 256 + g * 64;        // [q] stride 16 ints

  if (role < 2) {
    // ================= LAYER 0: half = role, cols = 4 gates x 128 units =================
    const int h = role;
    const int colu = h * 128 + w * 16 + u16;      // hidden unit 0..255 (this lane's column)
    // B fragments: bw[tau*8+s], tau=gate 0..3, s=K-step 0..7 (unit s*32..)
    s16x8 bw[32];
#pragma unroll
    for (int f = 0; f < 32; ++f) {
      const int tau = f >> 3, s = f & 7;
      const int col = tau * 256 + colu;
#pragma unroll
      for (int j = 0; j < 8; ++j) {
        const int k = s * 32 + kgrp * 8 + j;
        bw[f][j] = (short)f2bf(Wh0[(size_t)k * 1024 + col]);
      }
    }
    float bv[4], xv[4];
#pragma unroll
    for (int tau = 0; tau < 4; ++tau) {
      bv[tau] = b0v[tau * 256 + colu];
      xv[tau] = Wx0[tau * 256 + colu];
    }
    int* myflag = L0f + h * 16;
    int* pflag  = L0f + (1 - h) * 16;

    float c4[4] = {0.f, 0.f, 0.f, 0.f};

    for (int t = 0; t < TT; ++t) {
      if (t > 0 && tid == 0) wait_ge(pflag, t);   // partner published h0_{t-1}
      __syncthreads();

      // x for this lane's 4 rows (issued early; consumed at EW)
      float xr[4];
#pragma unroll
      for (int r = 0; r < 4; ++r)
        xr[r] = x[(size_t)(b0r + kgrp * 4 + r) * TT + t];

      f32x4 acc[4] = {{0,0,0,0},{0,0,0,0},{0,0,0,0},{0,0,0,0}};
      if (t > 0) {
        // partner half A-frags from global (L3), issued before own MFMAs to hide latency
        s16x8 ap[4];
        const unsigned short* sp = seq0 + ((size_t)(t - 1) * BB + b0r + arow) * HH;
#pragma unroll
        for (int i = 0; i < 4; ++i) {
          const int s = (1 - h) * 4 + i;
          ap[i] = *(const s16x8*)(sp + s * 32 + kgrp * 8);
        }
        // own half A-frags from swizzled LDS
        s16x8 ao[4];
        const char* hb = smem + ((t - 1) & 1) * 4096;
#pragma unroll
        for (int i = 0; i < 4; ++i) {
          const int off = (arow * 256 + (i * 32 + kgrp * 8) * 2) ^ ((arow & 7) << 4);
          ao[i] = *(const s16x8*)(hb + off);
        }
#pragma unroll
        for (int i = 0; i < 4; ++i) {        // own-half MFMAs (cover partner L3 latency)
          const int s = h * 4 + i;
#pragma unroll
          for (int tau = 0; tau < 4; ++tau) acc[tau] = MFMA(ao[i], bw[tau * 8 + s], acc[tau]);
        }
#pragma unroll
        for (int i = 0; i < 4; ++i) {        // partner-half MFMAs
          const int s = (1 - h) * 4 + i;
#pragma unroll
          for (int tau = 0; tau < 4; ++tau) acc[tau] = MFMA(ap[i], bw[tau * 8 + s], acc[tau]);
        }
      }
      // elementwise: lane owns unit `colu`, rows kgrp*4 + 0..3, all 4 gates in-register
      char* hwr = smem + (t & 1) * 4096;
#pragma unroll
      for (int r = 0; r < 4; ++r) {
        const int row = kgrp * 4 + r;
        const float gi = acc[0][r] + bv[0] + xr[r] * xv[0];
        const float gf = acc[1][r] + bv[1] + xr[r] * xv[1];
        const float gg = acc[2][r] + bv[2] + xr[r] * xv[2];
        const float go = acc[3][r] + bv[3] + xr[r] * xv[3];
        c4[r] = sigm(gf) * c4[r] + sigm(gi) * tanh_f(gg);
        const float hv = sigm(go) * tanh_f(c4[r]);
        const unsigned short hb16 = f2bf(hv);
        seq0[((size_t)t * BB + b0r + row) * HH + colu] = hb16;
        const int off = (row * 256 + (w * 16 + u16) * 2) ^ ((row & 7) << 4);
        *(unsigned short*)(hwr + off) = hb16;
      }
      __syncthreads();   // drains vmcnt: all waves' seq0 stores are in L2
      if (tid == 0)
        __hip_atomic_fetch_add(myflag, 1, __ATOMIC_RELEASE, __HIP_MEMORY_SCOPE_AGENT);
    }
  } else {
    // ================= LAYER 1: quarter q, cols = 4 gates x 64 units, K=512 =================
    const int q    = role - 2;
    const int grp  = w & 3;                 // 16-unit group within quarter
    const int g2   = (w >> 2) * 2;          // base gate for this wave (0 or 2)
    const int ucol = q * 64 + grp * 16 + u16;   // hidden unit (global)
    // B frags: bw[tau*16+s], tau=0,1 -> gate g2+tau; s=0..7 Wx1(h0), 8..15 Wh1(h1)
    s16x8 bw[32];
#pragma unroll
    for (int f = 0; f < 32; ++f) {
      const int tau = f >> 4, s = f & 15;
      const int col = (g2 + tau) * 256 + ucol;
#pragma unroll
      for (int j = 0; j < 8; ++j) {
        const int k = s * 32 + kgrp * 8 + j;
        const float wv = (k < 256) ? Wx1[(size_t)k * 1024 + col]
                                   : Wh1[(size_t)(k - 256) * 1024 + col];
        bw[f][j] = (short)f2bf(wv);
      }
    }
    // EW mapping: er = row 0..15, eu = even local unit; each thread: 2 units x 1 row
    const int er = tid >> 5;
    const int eu = (tid & 31) * 2;
    float bve[4][2];
#pragma unroll
    for (int gg2 = 0; gg2 < 4; ++gg2)
#pragma unroll
      for (int uu = 0; uu < 2; ++uu)
        bve[gg2][uu] = b1v[gg2 * 256 + q * 64 + eu + uu];

    int* myflag = L1f + q * 16;
    float* gbuf = (float*)smem;             // [16][264] f32
    float c2[2] = {0.f, 0.f}, hs2[2] = {0.f, 0.f};

    for (int t = 0; t < TT; ++t) {
      if (tid < 2) wait_ge(L0f + tid * 16, t + 1);          // h0_t fully published
      else if (t > 0 && tid < 5) {
        int qq = tid - 2; qq += (qq >= q);
        wait_ge(L1f + qq * 16, t);                          // peers published h1_{t-1}
      }
      __syncthreads();

      f32x4 acc[2] = {{0,0,0,0},{0,0,0,0}};
      s16x8 a0[8];
      const unsigned short* sp0 = seq0 + ((size_t)t * BB + b0r + arow) * HH;
#pragma unroll
      for (int s = 0; s < 8; ++s) a0[s] = *(const s16x8*)(sp0 + s * 32 + kgrp * 8);
      if (t > 0) {
        s16x8 a1[8];
        const unsigned short* rp = ring + ((size_t)((t - 1) & 1) * BB + b0r + arow) * HH;
#pragma unroll
        for (int s = 0; s < 8; ++s) a1[s] = *(const s16x8*)(rp + s * 32 + kgrp * 8);
#pragma unroll
        for (int s = 0; s < 8; ++s) {
          acc[0] = MFMA(a0[s], bw[s],      acc[0]);
          acc[1] = MFMA(a0[s], bw[16 + s], acc[1]);
        }
#pragma unroll
        for (int s = 0; s < 8; ++s) {
          acc[0] = MFMA(a1[s], bw[8 + s],       acc[0]);
          acc[1] = MFMA(a1[s], bw[16 + 8 + s],  acc[1]);
        }
      } else {
#pragma unroll
        for (int s = 0; s < 8; ++s) {
          acc[0] = MFMA(a0[s], bw[s],      acc[0]);
          acc[1] = MFMA(a0[s], bw[16 + s], acc[1]);
        }
      }
      // stage gates to LDS (cross-wave gate gather)
#pragma unroll
      for (int tau = 0; tau < 2; ++tau)
#pragma unroll
        for (int r = 0; r < 4; ++r)
          gbuf[(kgrp * 4 + r) * 264 + (g2 + tau) * 64 + grp * 16 + u16] = acc[tau][r];
      __syncthreads();

      unsigned int packed;
      {
        unsigned short hb16[2];
#pragma unroll
        for (int uu = 0; uu < 2; ++uu) {
          const int u = eu + uu;
          const float gi = gbuf[er * 264 +           u] + bve[0][uu];
          const float gf = gbuf[er * 264 +  64 +     u] + bve[1][uu];
          const float gg = gbuf[er * 264 + 128 +     u] + bve[2][uu];
          const float go = gbuf[er * 264 + 192 +     u] + bve[3][uu];
          c2[uu] = sigm(gf) * c2[uu] + sigm(gi) * tanh_f(gg);
          const float hv = sigm(go) * tanh_f(c2[uu]);
          hs2[uu] += hv;
          hb16[uu] = f2bf(hv);
        }
        packed = (unsigned int)hb16[0] | ((unsigned int)hb16[1] << 16);
      }
      *(unsigned int*)&ring[((size_t)(t & 1) * BB + b0r + er) * HH + q * 64 + eu] = packed;
      __syncthreads();   // drains vmcnt: ring stores in L2
      if (tid == 0)
        __hip_atomic_fetch_add(myflag, 1, __ATOMIC_RELEASE, __HIP_MEMORY_SCOPE_AGENT);
    }
#pragma unroll
    for (int uu = 0; uu < 2; ++uu)
      hmean[(size_t)(b0r + er) * HH + q * 64 + eu + uu] = hs2[uu] * (1.f / TT);
  }
}

__global__ __launch_bounds__(256)
void mlp_kernel(const float* __restrict__ theta, const float* __restrict__ Wtp,
                const float* __restrict__ btp, const float* __restrict__ Wl1,
                const float* __restrict__ bl1, const float* __restrict__ Wl2,
                const float* __restrict__ bl2, const float* __restrict__ Wo,
                const float* __restrict__ bo, const float* __restrict__ hmean,
                float* __restrict__ out)
{
  const int b = blockIdx.x;
  const int j = threadIdx.x;
  __shared__ float z[2 * HH];
  __shared__ float z1s[HH];
  __shared__ float red[256];

  float tp = btp[j];
#pragma unroll
  for (int d = 0; d < 5; ++d) tp += theta[b * 5 + d] * Wtp[d * HH + j];
  z[j] = hmean[(size_t)b * HH + j];
  z[HH + j] = tp;
  __syncthreads();

  float a1 = bl1[j];
  for (int k = 0; k < 2 * HH; ++k) a1 += z[k] * Wl1[(size_t)k * 256 + j];
  a1 = (a1 > 0.f) ? a1 : (__expf(a1) - 1.f);
  z1s[j] = a1;
  __syncthreads();

  float a2 = bl2[j];
  for (int k = 0; k < HH; ++k) a2 += z1s[k] * Wl2[(size_t)k * 256 + j];
  a2 = (a2 > 0.f) ? a2 : (__expf(a2) - 1.f);
  red[j] = a2 * Wo[j];
  __syncthreads();
  for (int s = 128; s > 0; s >>= 1) {
    if (j < s) red[j] += red[j + s];
    __syncthreads();
  }
  if (j == 0) out[b] = red[0] + bo[0];
}

extern "C" void kernel_launch(void* const* d_in, const int* in_sizes, int n_in,
                              void* d_out, int out_size, void* d_ws, size_t ws_size,
                              hipStream_t stream) {
  const float* x    = (const float*)d_in[0];
  const float* theta= (const float*)d_in[1];
  const float* Wx0  = (const float*)d_in[2];
  const float* Wh0  = (const float*)d_in[3];
  const float* b0   = (const float*)d_in[4];
  const float* Wx1  = (const float*)d_in[5];
  const float* Wh1  = (const float*)d_in[6];
  const float* b1   = (const float*)d_in[7];
  const float* Wtp  = (const float*)d_in[8];
  const float* btp  = (const float*)d_in[9];
  const float* Wl1  = (const float*)d_in[10];
  const float* bl1  = (const float*)d_in[11];
  const float* Wl2  = (const float*)d_in[12];
  const float* bl2  = (const float*)d_in[13];
  const float* Wo   = (const float*)d_in[14];
  const float* bo   = (const float*)d_in[15];

  // ws: flags (8KB, memset each launch) | ring bf16 [2][64][256] (64KB)
  //     | hmean f32 [64][256] (64KB) | seq0 bf16 [T][64][256] (64MB)
  char* ws = (char*)d_ws;
  int* flags           = (int*)ws;
  unsigned short* ring = (unsigned short*)(ws + 8192);
  float* hmean         = (float*)(ws + 8192 + 65536);
  unsigned short* seq0 = (unsigned short*)(ws + 8192 + 65536 + 65536);
  const size_t WS_NEED = 8192ull + 65536 + 65536 + (size_t)TT * BB * HH * 2ull;
  if (ws_size < WS_NEED) return;

  hipMemsetAsync(d_ws, 0, 8192, stream);

  lstm_kernel<<<dim3(48), dim3(512), 0, stream>>>(
      Wx0, Wh0, b0, Wx1, Wh1, b1, x, seq0, ring, hmean, flags);
  mlp_kernel<<<dim3(BB), dim3(256), 0, stream>>>(
      theta, Wtp, btp, Wl1, bl1, Wl2, bl2, Wo, bo, hmean, (float*)d_out);
}

// Round 3
// 11399.205 us; speedup vs baseline: 5.2689x; 1.8549x over previous
//
#include <hip/hip_runtime.h>
#include <hip/hip_bf16.h>

// LSTMModel_with_theta: B=64, T=2048, H=256, 2-layer LSTM -> mean_t -> MLP.
//
// Round 3: weights VGPR-resident for real this time.
//  - Wave = 2 gates x 16 units => 16 B-frags = 64 VGPRs (peak pressure ~140 << 256;
//    round-2's 128-frag waves pushed peak to ~240 and the compiler rematerialized
//    the weight loads into the t-loop: ~512KB/WG/step from L2 = the 10us/step).
//  - 4-wave WGs (256 thr). L0: 8 WGs/group (32 units each), K=256 full per wave.
//    L1: 16 WGs/group (16 units each), K=512 split across wave pairs:
//    khalf0 = Wx1 . h0_t (seq0), khalf1 = Wh1 . h1_{t-1} (ring).
//  - 4 batch groups x 16 rows; 96 WGs total, all co-resident.
//  - Sync: per-producer monotone flags (64B-padded), release store + acquire poll
//    (the acquire's L1 invalidate keeps reused ring slots coherent).
//  - Gate gather + khalf reduction via one padded LDS buffer; 3 barriers/step.

#define BB 64
#define TT 2048
#define HH 256

typedef short s16x8 __attribute__((ext_vector_type(8)));
typedef float f32x4 __attribute__((ext_vector_type(4)));

__device__ inline unsigned short f2bf(float f) {
  unsigned u = __float_as_uint(f);
  u += 0x7fff + ((u >> 16) & 1);          // RNE
  return (unsigned short)(u >> 16);
}
__device__ inline float sigm(float x) { return 1.f / (1.f + __expf(-x)); }
__device__ inline float tanh_f(float x) { return 1.f - 2.f / (__expf(2.f * x) + 1.f); }

__device__ inline void wait_ge(const int* p, int tgt) {
  if (__hip_atomic_load(p, __ATOMIC_ACQUIRE, __HIP_MEMORY_SCOPE_AGENT) >= tgt) return;
  while (__hip_atomic_load(p, __ATOMIC_ACQUIRE, __HIP_MEMORY_SCOPE_AGENT) < tgt)
    __builtin_amdgcn_s_sleep(1);
}

#define MFMA(a, b, c) __builtin_amdgcn_mfma_f32_16x16x32_bf16((a), (b), (c), 0, 0, 0)

__global__ void xt_kernel(const float* __restrict__ x, float* __restrict__ xT) {
  int i = blockIdx.x * 256 + threadIdx.x;   // 131072 total
  int b = i & 63, t = i >> 6;
  xT[(size_t)t * BB + b] = x[(size_t)b * TT + t];
}

__global__ __launch_bounds__(256, 2)
void lstm_kernel(const float* __restrict__ Wx0, const float* __restrict__ Wh0,
                 const float* __restrict__ b0v,
                 const float* __restrict__ Wx1, const float* __restrict__ Wh1,
                 const float* __restrict__ b1v,
                 const float* __restrict__ xT,
                 unsigned short* __restrict__ seq0, unsigned short* __restrict__ ring,
                 float* __restrict__ hmean, int* flags)
{
  __shared__ float gbuf[2][16][4][33];   // [khalf|0][row][gate][unit(pad)]

  const int tid  = threadIdx.x;
  const int lane = tid & 63;
  const int w    = tid >> 6;        // wave 0..3
  const int u16  = lane & 15;
  const int kgrp = lane >> 4;
  const int arow = lane & 15;
  const int gp   = w & 1;           // gate pair: gates 2gp, 2gp+1

  int* f0 = flags;                  // [(g*8+p)*16]
  int* f1 = flags + 512;            // [(g*16+q)*16]

  const int bid = blockIdx.x;
  const int eur = tid >> 4, eul = tid & 15;   // EW: row, unit-lane

  if (bid < 32) {
    // ================= LAYER 0: 8 WGs/group, 32 units each, K=256 =================
    const int g = bid >> 3, wg = bid & 7;
    const int b0r = g * 16;
    const int uh = w >> 1;                       // unit half within WG
    const int ubase = wg * 32;
    s16x8 bw[16];                                // [nt*8+ks] : 64 VGPRs
#pragma unroll
    for (int f = 0; f < 16; ++f) {
      const int nt = f >> 3, ks = f & 7;
      const int col = (2 * gp + nt) * 256 + ubase + uh * 16 + u16;
#pragma unroll
      for (int j = 0; j < 8; ++j)
        bw[f][j] = (short)f2bf(Wh0[(size_t)(ks * 32 + kgrp * 8 + j) * 1024 + col]);
    }
    float bE[2][4], xE[2][4];
#pragma unroll
    for (int uu = 0; uu < 2; ++uu)
#pragma unroll
      for (int ga = 0; ga < 4; ++ga) {
        const int col = ga * 256 + ubase + eul + uu * 16;
        bE[uu][ga] = b0v[col];
        xE[uu][ga] = Wx0[col];
      }
    int* myflag = &f0[(g * 8 + wg) * 16];
    float cst[2] = {0.f, 0.f};

    for (int t = 0; t < TT; ++t) {
      if (t > 0 && tid < 8) wait_ge(&f0[(g * 8 + tid) * 16], t);
      __syncthreads();

      f32x4 acc0 = {0, 0, 0, 0}, acc1 = {0, 0, 0, 0};
      if (t > 0) {
        const unsigned short* sp = seq0 + ((size_t)(t - 1) * BB + b0r + arow) * HH;
        s16x8 a[8];
#pragma unroll
        for (int ks = 0; ks < 8; ++ks) a[ks] = *(const s16x8*)(sp + ks * 32 + kgrp * 8);
#pragma unroll
        for (int ks = 0; ks < 8; ++ks) {
          acc0 = MFMA(a[ks], bw[ks], acc0);
          acc1 = MFMA(a[ks], bw[8 + ks], acc1);
        }
      }
#pragma unroll
      for (int r = 0; r < 4; ++r) {
        gbuf[0][kgrp * 4 + r][2 * gp + 0][uh * 16 + u16] = acc0[r];
        gbuf[0][kgrp * 4 + r][2 * gp + 1][uh * 16 + u16] = acc1[r];
      }
      __syncthreads();

      const float xval = xT[(size_t)t * BB + b0r + eur];
      unsigned short hb[2];
#pragma unroll
      for (int uu = 0; uu < 2; ++uu) {
        const int ul = eul + uu * 16;
        const float gi = gbuf[0][eur][0][ul] + bE[uu][0] + xval * xE[uu][0];
        const float gf = gbuf[0][eur][1][ul] + bE[uu][1] + xval * xE[uu][1];
        const float gg = gbuf[0][eur][2][ul] + bE[uu][2] + xval * xE[uu][2];
        const float go = gbuf[0][eur][3][ul] + bE[uu][3] + xval * xE[uu][3];
        cst[uu] = sigm(gf) * cst[uu] + sigm(gi) * tanh_f(gg);
        const float hv = sigm(go) * tanh_f(cst[uu]);
        hb[uu] = f2bf(hv);
      }
      unsigned short* dp = seq0 + ((size_t)t * BB + b0r + eur) * HH + ubase;
      dp[eul]      = hb[0];
      dp[eul + 16] = hb[1];
      __syncthreads();   // drains vmcnt before flag
      if (tid == 0)
        __hip_atomic_store(myflag, t + 1, __ATOMIC_RELEASE, __HIP_MEMORY_SCOPE_AGENT);
    }
  } else {
    // ================= LAYER 1: 16 WGs/group, 16 units each, K=512 split =================
    const int idx = bid - 32;
    const int g = idx >> 4, q = idx & 15;
    const int b0r = g * 16;
    const int kh = w >> 1;                       // K half: 0=Wx1.h0_t, 1=Wh1.h1_{t-1}
    s16x8 bw[16];
#pragma unroll
    for (int f = 0; f < 16; ++f) {
      const int nt = f >> 3, ks = f & 7;
      const int col = (2 * gp + nt) * 256 + q * 16 + u16;
#pragma unroll
      for (int j = 0; j < 8; ++j) {
        const int k = ks * 32 + kgrp * 8 + j;
        const float wv = (kh == 0) ? Wx1[(size_t)k * 1024 + col]
                                   : Wh1[(size_t)k * 1024 + col];
        bw[f][j] = (short)f2bf(wv);
      }
    }
    float bE[4];
#pragma unroll
    for (int ga = 0; ga < 4; ++ga) bE[ga] = b1v[ga * 256 + q * 16 + eul];
    int* myflag = &f1[(g * 16 + q) * 16];
    float cst = 0.f, hsum = 0.f;

    for (int t = 0; t < TT; ++t) {
      if (tid < 8) wait_ge(&f0[(g * 8 + tid) * 16], t + 1);
      else if (t > 0 && tid < 24) wait_ge(&f1[(g * 16 + tid - 8) * 16], t);
      __syncthreads();

      f32x4 acc0 = {0, 0, 0, 0}, acc1 = {0, 0, 0, 0};
      if (kh == 0) {
        const unsigned short* sp = seq0 + ((size_t)t * BB + b0r + arow) * HH;
        s16x8 a[8];
#pragma unroll
        for (int ks = 0; ks < 8; ++ks) a[ks] = *(const s16x8*)(sp + ks * 32 + kgrp * 8);
#pragma unroll
        for (int ks = 0; ks < 8; ++ks) {
          acc0 = MFMA(a[ks], bw[ks], acc0);
          acc1 = MFMA(a[ks], bw[8 + ks], acc1);
        }
      } else if (t > 0) {
        const unsigned short* rp = ring + ((size_t)((t - 1) & 1) * BB + b0r + arow) * HH;
        s16x8 a[8];
#pragma unroll
        for (int ks = 0; ks < 8; ++ks) a[ks] = *(const s16x8*)(rp + ks * 32 + kgrp * 8);
#pragma unroll
        for (int ks = 0; ks < 8; ++ks) {
          acc0 = MFMA(a[ks], bw[ks], acc0);
          acc1 = MFMA(a[ks], bw[8 + ks], acc1);
        }
      }
#pragma unroll
      for (int r = 0; r < 4; ++r) {
        gbuf[kh][kgrp * 4 + r][2 * gp + 0][u16] = acc0[r];
        gbuf[kh][kgrp * 4 + r][2 * gp + 1][u16] = acc1[r];
      }
      __syncthreads();

      const float gi = gbuf[0][eur][0][eul] + gbuf[1][eur][0][eul] + bE[0];
      const float gf = gbuf[0][eur][1][eul] + gbuf[1][eur][1][eul] + bE[1];
      const float gg = gbuf[0][eur][2][eul] + gbuf[1][eur][2][eul] + bE[2];
      const float go = gbuf[0][eur][3][eul] + gbuf[1][eur][3][eul] + bE[3];
      cst = sigm(gf) * cst + sigm(gi) * tanh_f(gg);
      const float hv = sigm(go) * tanh_f(cst);
      hsum += hv;
      ring[((size_t)(t & 1) * BB + b0r + eur) * HH + q * 16 + eul] = f2bf(hv);
      __syncthreads();   // drains vmcnt before flag
      if (tid == 0)
        __hip_atomic_store(myflag, t + 1, __ATOMIC_RELEASE, __HIP_MEMORY_SCOPE_AGENT);
    }
    hmean[(size_t)(b0r + eur) * HH + q * 16 + eul] = hsum * (1.f / TT);
  }
}

__global__ __launch_bounds__(256)
void mlp_kernel(const float* __restrict__ theta, const float* __restrict__ Wtp,
                const float* __restrict__ btp, const float* __restrict__ Wl1,
                const float* __restrict__ bl1, const float* __restrict__ Wl2,
                const float* __restrict__ bl2, const float* __restrict__ Wo,
                const float* __restrict__ bo, const float* __restrict__ hmean,
                float* __restrict__ out)
{
  const int b = blockIdx.x;
  const int j = threadIdx.x;
  __shared__ float z[2 * HH];
  __shared__ float z1s[HH];
  __shared__ float red[256];

  float tp = btp[j];
#pragma unroll
  for (int d = 0; d < 5; ++d) tp += theta[b * 5 + d] * Wtp[d * HH + j];
  z[j] = hmean[(size_t)b * HH + j];
  z[HH + j] = tp;
  __syncthreads();

  float a1 = bl1[j];
  for (int k = 0; k < 2 * HH; ++k) a1 += z[k] * Wl1[(size_t)k * 256 + j];
  a1 = (a1 > 0.f) ? a1 : (__expf(a1) - 1.f);
  z1s[j] = a1;
  __syncthreads();

  float a2 = bl2[j];
  for (int k = 0; k < HH; ++k) a2 += z1s[k] * Wl2[(size_t)k * 256 + j];
  a2 = (a2 > 0.f) ? a2 : (__expf(a2) - 1.f);
  red[j] = a2 * Wo[j];
  __syncthreads();
  for (int s = 128; s > 0; s >>= 1) {
    if (j < s) red[j] += red[j + s];
    __syncthreads();
  }
  if (j == 0) out[b] = red[0] + bo[0];
}

extern "C" void kernel_launch(void* const* d_in, const int* in_sizes, int n_in,
                              void* d_out, int out_size, void* d_ws, size_t ws_size,
                              hipStream_t stream) {
  const float* x    = (const float*)d_in[0];
  const float* theta= (const float*)d_in[1];
  const float* Wx0  = (const float*)d_in[2];
  const float* Wh0  = (const float*)d_in[3];
  const float* b0   = (const float*)d_in[4];
  const float* Wx1  = (const float*)d_in[5];
  const float* Wh1  = (const float*)d_in[6];
  const float* b1   = (const float*)d_in[7];
  const float* Wtp  = (const float*)d_in[8];
  const float* btp  = (const float*)d_in[9];
  const float* Wl1  = (const float*)d_in[10];
  const float* bl1  = (const float*)d_in[11];
  const float* Wl2  = (const float*)d_in[12];
  const float* bl2  = (const float*)d_in[13];
  const float* Wo   = (const float*)d_in[14];
  const float* bo   = (const float*)d_in[15];

  // ws: flags 8KB | ring bf16 [2][64][256] 64KB | hmean f32 64KB | xT f32 512KB | seq0 bf16 [T][64][256] 64MB
  char* ws = (char*)d_ws;
  int* flags           = (int*)ws;
  unsigned short* ring = (unsigned short*)(ws + 8192);
  float* hmean         = (float*)(ws + 8192 + 65536);
  float* xT            = (float*)(ws + 8192 + 65536 + 65536);
  unsigned short* seq0 = (unsigned short*)(ws + 8192 + 65536 + 65536 + 524288);
  const size_t WS_NEED = 8192ull + 65536 + 65536 + 524288 + (size_t)TT * BB * HH * 2ull;
  if (ws_size < WS_NEED) return;

  hipMemsetAsync(d_ws, 0, 8192, stream);

  xt_kernel<<<dim3((BB * TT) / 256), dim3(256), 0, stream>>>(x, xT);
  lstm_kernel<<<dim3(96), dim3(256), 0, stream>>>(
      Wx0, Wh0, b0, Wx1, Wh1, b1, xT, seq0, ring, hmean, flags);
  mlp_kernel<<<dim3(BB), dim3(256), 0, stream>>>(
      theta, Wtp, btp, Wl1, bl1, Wl2, bl2, Wo, bo, hmean, (float*)d_out);
}

// Round 4
// 6680.748 us; speedup vs baseline: 8.9903x; 1.7063x over previous
//
#include <hip/hip_runtime.h>
#include <hip/hip_bf16.h>

// LSTMModel_with_theta: B=64, T=2048, H=256, 2-layer LSTM -> mean_t -> MLP.
//
// Round 4: same decomposition as round 3 (weights VGPR-resident, 96 WGs),
// but cross-WG sync rebuilt with ZERO bulk cache-maintenance ops:
//  - r3 polled with ACQUIRE loads (bulk invalidate per poll iteration) and
//    published with RELEASE (buffer_wbl2 per step) -> continuous L2 wipe-out:
//    599MB fabric refetch, 11.5ms with 42ms outliers.
//  - Now: producers write shared data WRITE-THROUGH (relaxed agent atomic
//    stores -> sc0 sc1, land at MALL); __syncthreads drains vmcnt (write acks);
//    flag published with RELAXED atomic store. Consumers poll with RELAXED
//    atomic loads; reused buffers (ring) read via relaxed atomic loads
//    (L1/L2 bypass); append-only seq0 read with plain cached loads (always
//    cold lines -> no staleness, and weights/x/bias stay hot in L1/L2).
//  - Placement-independent: coherence point is the chip-global MALL.

#define BB 64
#define TT 2048
#define HH 256

typedef short s16x8 __attribute__((ext_vector_type(8)));
typedef float f32x4 __attribute__((ext_vector_type(4)));

__device__ inline unsigned short f2bf(float f) {
  unsigned u = __float_as_uint(f);
  u += 0x7fff + ((u >> 16) & 1);          // RNE
  return (unsigned short)(u >> 16);
}
__device__ inline float sigm(float x) { return 1.f / (1.f + __expf(-x)); }
__device__ inline float tanh_f(float x) { return 1.f - 2.f / (__expf(2.f * x) + 1.f); }

// write-through (coherence-point) ops: no cache maintenance emitted
__device__ inline void st_wt32(unsigned int* p, unsigned int v) {
  __hip_atomic_store(p, v, __ATOMIC_RELAXED, __HIP_MEMORY_SCOPE_AGENT);
}
__device__ inline void st_flag(int* p, int v) {
  __hip_atomic_store(p, v, __ATOMIC_RELAXED, __HIP_MEMORY_SCOPE_AGENT);
}
__device__ inline unsigned long long ld_wt64(const unsigned long long* p) {
  return __hip_atomic_load(p, __ATOMIC_RELAXED, __HIP_MEMORY_SCOPE_AGENT);
}
__device__ inline void wait_ge(const int* p, int tgt) {
  while (__hip_atomic_load(p, __ATOMIC_RELAXED, __HIP_MEMORY_SCOPE_AGENT) < tgt)
    __builtin_amdgcn_s_sleep(1);
}
__device__ inline s16x8 ld_frag_wt(const unsigned short* p) {
  union { unsigned long long q[2]; s16x8 v; } u;
  u.q[0] = ld_wt64((const unsigned long long*)p);
  u.q[1] = ld_wt64((const unsigned long long*)(p + 4));
  return u.v;
}

#define MFMA(a, b, c) __builtin_amdgcn_mfma_f32_16x16x32_bf16((a), (b), (c), 0, 0, 0)

__global__ void xt_kernel(const float* __restrict__ x, float* __restrict__ xT) {
  int i = blockIdx.x * 256 + threadIdx.x;   // 131072 total
  int b = i & 63, t = i >> 6;
  xT[(size_t)t * BB + b] = x[(size_t)b * TT + t];
}

__global__ __launch_bounds__(256, 2)
void lstm_kernel(const float* __restrict__ Wx0, const float* __restrict__ Wh0,
                 const float* __restrict__ b0v,
                 const float* __restrict__ Wx1, const float* __restrict__ Wh1,
                 const float* __restrict__ b1v,
                 const float* __restrict__ xT,
                 unsigned short* __restrict__ seq0, unsigned short* __restrict__ ring,
                 float* __restrict__ hmean, int* flags)
{
  __shared__ float gbuf[2][16][4][33];   // [khalf|0][row][gate][unit(pad)]

  const int tid  = threadIdx.x;
  const int lane = tid & 63;
  const int w    = tid >> 6;        // wave 0..3
  const int u16  = lane & 15;
  const int kgrp = lane >> 4;
  const int arow = lane & 15;
  const int gp   = w & 1;           // gate pair: gates 2gp, 2gp+1

  int* f0 = flags;                  // [(g*8+p)*16]
  int* f1 = flags + 512;            // [(g*16+q)*16]

  const int bid = blockIdx.x;

  if (bid < 32) {
    // ================= LAYER 0: 8 WGs/group, 32 units each, K=256 =================
    const int g = bid >> 3, wg = bid & 7;
    const int b0r = g * 16;
    const int uh = w >> 1;                       // unit half within WG
    const int ubase = wg * 32;
    s16x8 bw[16];                                // [nt*8+ks] : 64 VGPRs
#pragma unroll
    for (int f = 0; f < 16; ++f) {
      const int nt = f >> 3, ks = f & 7;
      const int col = (2 * gp + nt) * 256 + ubase + uh * 16 + u16;
#pragma unroll
      for (int j = 0; j < 8; ++j)
        bw[f][j] = (short)f2bf(Wh0[(size_t)(ks * 32 + kgrp * 8 + j) * 1024 + col]);
    }
    // EW: row = tid>>4, unit pair (eu2, eu2+1) -> packed u32 write-through store
    const int eur = tid >> 4;
    const int eu2 = (tid & 15) * 2;
    float bE[2][4], xE[2][4];
#pragma unroll
    for (int uu = 0; uu < 2; ++uu)
#pragma unroll
      for (int ga = 0; ga < 4; ++ga) {
        const int col = ga * 256 + ubase + eu2 + uu;
        bE[uu][ga] = b0v[col];
        xE[uu][ga] = Wx0[col];
      }
    int* myflag = &f0[(g * 8 + wg) * 16];
    float cst[2] = {0.f, 0.f};

    for (int t = 0; t < TT; ++t) {
      if (t > 0 && tid < 8) wait_ge(&f0[(g * 8 + tid) * 16], t);
      __syncthreads();

      f32x4 acc0 = {0, 0, 0, 0}, acc1 = {0, 0, 0, 0};
      if (t > 0) {
        // append-only seq0: plain cached loads (cold lines, no staleness)
        const unsigned short* sp = seq0 + ((size_t)(t - 1) * BB + b0r + arow) * HH;
        s16x8 a[8];
#pragma unroll
        for (int ks = 0; ks < 8; ++ks) a[ks] = *(const s16x8*)(sp + ks * 32 + kgrp * 8);
#pragma unroll
        for (int ks = 0; ks < 8; ++ks) {
          acc0 = MFMA(a[ks], bw[ks], acc0);
          acc1 = MFMA(a[ks], bw[8 + ks], acc1);
        }
      }
#pragma unroll
      for (int r = 0; r < 4; ++r) {
        gbuf[0][kgrp * 4 + r][2 * gp + 0][uh * 16 + u16] = acc0[r];
        gbuf[0][kgrp * 4 + r][2 * gp + 1][uh * 16 + u16] = acc1[r];
      }
      __syncthreads();

      const float xval = xT[(size_t)t * BB + b0r + eur];
      unsigned short hb[2];
#pragma unroll
      for (int uu = 0; uu < 2; ++uu) {
        const int ul = eu2 + uu;
        const float gi = gbuf[0][eur][0][ul] + bE[uu][0] + xval * xE[uu][0];
        const float gf = gbuf[0][eur][1][ul] + bE[uu][1] + xval * xE[uu][1];
        const float gg = gbuf[0][eur][2][ul] + bE[uu][2] + xval * xE[uu][2];
        const float go = gbuf[0][eur][3][ul] + bE[uu][3] + xval * xE[uu][3];
        cst[uu] = sigm(gf) * cst[uu] + sigm(gi) * tanh_f(gg);
        const float hv = sigm(go) * tanh_f(cst[uu]);
        hb[uu] = f2bf(hv);
      }
      // write-through packed store (reaches MALL; acked before flag via barrier's vmcnt drain)
      st_wt32((unsigned int*)(seq0 + ((size_t)t * BB + b0r + eur) * HH + ubase + eu2),
              (unsigned int)hb[0] | ((unsigned int)hb[1] << 16));
      __syncthreads();   // drains vmcnt: write-through stores acked
      if (tid == 0) st_flag(myflag, t + 1);
    }
  } else {
    // ================= LAYER 1: 16 WGs/group, 16 units each, K=512 split =================
    const int idx = bid - 32;
    const int g = idx >> 4, q = idx & 15;
    const int b0r = g * 16;
    const int kh = w >> 1;                       // K half: 0=Wx1.h0_t, 1=Wh1.h1_{t-1}
    s16x8 bw[16];
#pragma unroll
    for (int f = 0; f < 16; ++f) {
      const int nt = f >> 3, ks = f & 7;
      const int col = (2 * gp + nt) * 256 + q * 16 + u16;
#pragma unroll
      for (int j = 0; j < 8; ++j) {
        const int k = ks * 32 + kgrp * 8 + j;
        const float wv = (kh == 0) ? Wx1[(size_t)k * 1024 + col]
                                   : Wh1[(size_t)k * 1024 + col];
        bw[f][j] = (short)f2bf(wv);
      }
    }
    // EW: 128 active threads, row = tid>>3, unit pair (eu2, eu2+1)
    const int eur = tid >> 3;
    const int eu2 = (tid & 7) * 2;
    float bE[2][4];
#pragma unroll
    for (int uu = 0; uu < 2; ++uu)
#pragma unroll
      for (int ga = 0; ga < 4; ++ga)
        bE[uu][ga] = b1v[ga * 256 + q * 16 + eu2 + uu];
    int* myflag = &f1[(g * 16 + q) * 16];
    float cst[2] = {0.f, 0.f}, hs2[2] = {0.f, 0.f};

    for (int t = 0; t < TT; ++t) {
      if (tid < 8) wait_ge(&f0[(g * 8 + tid) * 16], t + 1);
      else if (t > 0 && tid < 24) wait_ge(&f1[(g * 16 + tid - 8) * 16], t);
      __syncthreads();

      f32x4 acc0 = {0, 0, 0, 0}, acc1 = {0, 0, 0, 0};
      if (kh == 0) {
        const unsigned short* sp = seq0 + ((size_t)t * BB + b0r + arow) * HH;
        s16x8 a[8];
#pragma unroll
        for (int ks = 0; ks < 8; ++ks) a[ks] = *(const s16x8*)(sp + ks * 32 + kgrp * 8);
#pragma unroll
        for (int ks = 0; ks < 8; ++ks) {
          acc0 = MFMA(a[ks], bw[ks], acc0);
          acc1 = MFMA(a[ks], bw[8 + ks], acc1);
        }
      } else if (t > 0) {
        // ring slots are reused: bypass L1/L2 (relaxed atomic 2x u64 loads)
        const unsigned short* rp = ring + ((size_t)((t - 1) & 1) * BB + b0r + arow) * HH;
        s16x8 a[8];
#pragma unroll
        for (int ks = 0; ks < 8; ++ks) a[ks] = ld_frag_wt(rp + ks * 32 + kgrp * 8);
#pragma unroll
        for (int ks = 0; ks < 8; ++ks) {
          acc0 = MFMA(a[ks], bw[ks], acc0);
          acc1 = MFMA(a[ks], bw[8 + ks], acc1);
        }
      }
#pragma unroll
      for (int r = 0; r < 4; ++r) {
        gbuf[kh][kgrp * 4 + r][2 * gp + 0][u16] = acc0[r];
        gbuf[kh][kgrp * 4 + r][2 * gp + 1][u16] = acc1[r];
      }
      __syncthreads();

      if (tid < 128) {
        unsigned short hb[2];
#pragma unroll
        for (int uu = 0; uu < 2; ++uu) {
          const int ul = eu2 + uu;
          const float gi = gbuf[0][eur][0][ul] + gbuf[1][eur][0][ul] + bE[uu][0];
          const float gf = gbuf[0][eur][1][ul] + gbuf[1][eur][1][ul] + bE[uu][1];
          const float gg = gbuf[0][eur][2][ul] + gbuf[1][eur][2][ul] + bE[uu][2];
          const float go = gbuf[0][eur][3][ul] + gbuf[1][eur][3][ul] + bE[uu][3];
          cst[uu] = sigm(gf) * cst[uu] + sigm(gi) * tanh_f(gg);
          const float hv = sigm(go) * tanh_f(cst[uu]);
          hs2[uu] += hv;
          hb[uu] = f2bf(hv);
        }
        st_wt32((unsigned int*)(ring + ((size_t)(t & 1) * BB + b0r + eur) * HH + q * 16 + eu2),
                (unsigned int)hb[0] | ((unsigned int)hb[1] << 16));
      }
      __syncthreads();   // drains vmcnt: write-through stores acked
      if (tid == 0) st_flag(myflag, t + 1);
    }
    if (tid < 128) {
#pragma unroll
      for (int uu = 0; uu < 2; ++uu)
        hmean[(size_t)(b0r + eur) * HH + q * 16 + eu2 + uu] = hs2[uu] * (1.f / TT);
    }
  }
}

__global__ __launch_bounds__(256)
void mlp_kernel(const float* __restrict__ theta, const float* __restrict__ Wtp,
                const float* __restrict__ btp, const float* __restrict__ Wl1,
                const float* __restrict__ bl1, const float* __restrict__ Wl2,
                const float* __restrict__ bl2, const float* __restrict__ Wo,
                const float* __restrict__ bo, const float* __restrict__ hmean,
                float* __restrict__ out)
{
  const int b = blockIdx.x;
  const int j = threadIdx.x;
  __shared__ float z[2 * HH];
  __shared__ float z1s[HH];
  __shared__ float red[256];

  float tp = btp[j];
#pragma unroll
  for (int d = 0; d < 5; ++d) tp += theta[b * 5 + d] * Wtp[d * HH + j];
  z[j] = hmean[(size_t)b * HH + j];
  z[HH + j] = tp;
  __syncthreads();

  float a1 = bl1[j];
  for (int k = 0; k < 2 * HH; ++k) a1 += z[k] * Wl1[(size_t)k * 256 + j];
  a1 = (a1 > 0.f) ? a1 : (__expf(a1) - 1.f);
  z1s[j] = a1;
  __syncthreads();

  float a2 = bl2[j];
  for (int k = 0; k < HH; ++k) a2 += z1s[k] * Wl2[(size_t)k * 256 + j];
  a2 = (a2 > 0.f) ? a2 : (__expf(a2) - 1.f);
  red[j] = a2 * Wo[j];
  __syncthreads();
  for (int s = 128; s > 0; s >>= 1) {
    if (j < s) red[j] += red[j + s];
    __syncthreads();
  }
  if (j == 0) out[b] = red[0] + bo[0];
}

extern "C" void kernel_launch(void* const* d_in, const int* in_sizes, int n_in,
                              void* d_out, int out_size, void* d_ws, size_t ws_size,
                              hipStream_t stream) {
  const float* x    = (const float*)d_in[0];
  const float* theta= (const float*)d_in[1];
  const float* Wx0  = (const float*)d_in[2];
  const float* Wh0  = (const float*)d_in[3];
  const float* b0   = (const float*)d_in[4];
  const float* Wx1  = (const float*)d_in[5];
  const float* Wh1  = (const float*)d_in[6];
  const float* b1   = (const float*)d_in[7];
  const float* Wtp  = (const float*)d_in[8];
  const float* btp  = (const float*)d_in[9];
  const float* Wl1  = (const float*)d_in[10];
  const float* bl1  = (const float*)d_in[11];
  const float* Wl2  = (const float*)d_in[12];
  const float* bl2  = (const float*)d_in[13];
  const float* Wo   = (const float*)d_in[14];
  const float* bo   = (const float*)d_in[15];

  // ws: flags 8KB | ring bf16 [2][64][256] 64KB | hmean f32 64KB | xT f32 512KB | seq0 bf16 [T][64][256] 64MB
  char* ws = (char*)d_ws;
  int* flags           = (int*)ws;
  unsigned short* ring = (unsigned short*)(ws + 8192);
  float* hmean         = (float*)(ws + 8192 + 65536);
  float* xT            = (float*)(ws + 8192 + 65536 + 65536);
  unsigned short* seq0 = (unsigned short*)(ws + 8192 + 65536 + 65536 + 524288);
  const size_t WS_NEED = 8192ull + 65536 + 65536 + 524288 + (size_t)TT * BB * HH * 2ull;
  if (ws_size < WS_NEED) return;

  hipMemsetAsync(d_ws, 0, 8192, stream);

  xt_kernel<<<dim3((BB * TT) / 256), dim3(256), 0, stream>>>(x, xT);
  lstm_kernel<<<dim3(96), dim3(256), 0, stream>>>(
      Wx0, Wh0, b0, Wx1, Wh1, b1, xT, seq0, ring, hmean, flags);
  mlp_kernel<<<dim3(BB), dim3(256), 0, stream>>>(
      theta, Wtp, btp, Wl1, bl1, Wl2, bl2, Wo, bo, hmean, (float*)d_out);
}